// Round 9
// baseline (306.149 us; speedup 1.0000x reference)
//
#include <hip/hip_runtime.h>
#include <hip/hip_bf16.h>
#include <math.h>

#define WW     160
#define NBATCH 4
#define VOL    (160*160*160)      // 4,096,000
#define PLANE  (160*160)

#define C1f 0.0001f
#define C2f 0.0009f

#define RUN_H 16                  // h outputs per k_wh block
#define NROWS (RUN_H + 10)        // 26 rows staged
#define LDW   176                 // padded cols: [0..4]=0, [5..164]=data, [165..175]=0
#define RUN_D 40                  // d outputs per k_dssim block (4 segments)
#define ITERS (RUN_D + 10)        // 50
#define PF    8                   // prefetch slots (R2 anchor; PF=16 was null)
#define NBLK_B (100 * 4 * 4)      // k_dssim block count = 1600

typedef float v2f __attribute__((ext_vector_type(2)));

struct Gw { float g[11]; };

__device__ __forceinline__ float bf2f(unsigned short u) {
    return __uint_as_float(((unsigned int)u) << 16);
}
__device__ __forceinline__ unsigned short f2bf(float f) {
    __hip_bfloat16 h = __float2bfloat16(f);   // RNE
    return *reinterpret_cast<unsigned short*>(&h);
}

// ---------------- Pass A: W+H conv fused; bf16x2-packed LDS tile ----------------
// R2 VERBATIM compute (148.3 us anchor), single launch again (R8's half-split
// cost 18 us of tail and is reverted). ONLY addition: block (0,0,0) zeroes
// accum+ctr, replacing the hipMemsetAsync dispatch (stream order guarantees
// k_dssim sees the zeroes; kernel boundary is a device-wide fence).
// block 192 (3 waves; threads 0..159 compute, all 192 load)
// grid (10, d=160, batch=4) = 6400 blocks; LDS 18.3 KB -> 8 blocks/CU.
__global__ __launch_bounds__(192, 4) void k_wh(
    const float* __restrict__ x, const float* __restrict__ y,
    ushort4* __restrict__ B4, Gw gw,
    double* __restrict__ accum, unsigned int* __restrict__ ctr)
{
    __shared__ unsigned int tile[NROWS][LDW];   // 26*176*4 = 18.3 KB
    const int t  = threadIdx.x;
    const int h0 = blockIdx.x * RUN_H;
    const int d  = blockIdx.y;
    const int n  = blockIdx.z;

    if (t == 0 && blockIdx.x == 0 && d == 0 && n == 0) {
        accum[0] = 0.0;         // replaces hipMemsetAsync dispatch
        ctr[0]   = 0u;          // completion counter for fused finalizer
    }

    const float* xb = x + (size_t)n * VOL + (size_t)d * PLANE;
    const float* yb = y + (size_t)n * VOL + (size_t)d * PLANE;

    // ---- fill tile: independent coalesced loads, pack bf16(y)<<16 | bf16(x) ----
#pragma unroll 4
    for (int s = t; s < NROWS * LDW; s += 192) {
        int r = s / LDW, c = s - r * LDW;
        int h = h0 - 5 + r;
        int w = c - 5;
        float vx = 0.f, vy = 0.f;
        if (h >= 0 && h < 160 && w >= 0 && w < 160) {
            size_t idx = (size_t)h * WW + w;
            vx = xb[idx];
            vy = yb[idx];
        }
        tile[r][c] = ((unsigned int)f2bf(vy) << 16) | (unsigned int)f2bf(vx);
    }
    __syncthreads();

    // ---- compute: LDS u32 taps (2-bitop unpack) + packed-f32 VALU ----
    if (t < 160) {
        const int w = t;
        const size_t outbase = (size_t)n * VOL + (size_t)d * PLANE + w;
        v2f r01[11];          // ring: {conv(x), conv(y)}
        v2f r23[11];          // ring: {conv(x^2)+conv(y^2), conv(xy)} packed

        // Macro-unrolled rows: every ring index is a literal.
#define WSTEP(i) { \
        v2f a01 = {0.f, 0.f}, a23 = {0.f, 0.f}; float a4 = 0.f; \
        _Pragma("unroll") \
        for (int k = 0; k < 5; ++k) { \
            unsigned int u1 = tile[i][w + k]; \
            unsigned int u2 = tile[i][w + 10 - k]; \
            v2f p1 = { __uint_as_float(u1 << 16), __uint_as_float(u1 & 0xffff0000u) }; \
            v2f p2 = { __uint_as_float(u2 << 16), __uint_as_float(u2 & 0xffff0000u) }; \
            float g = gw.g[k]; v2f g2 = {g, g}; \
            a01 += g2 * (p1 + p2); \
            v2f sq = p1 * p1; \
            sq += p2 * p2; \
            a23 += g2 * sq; \
            float pr = p1.x * p1.y; \
            pr = fmaf(p2.x, p2.y, pr); \
            a4 = fmaf(g, pr, a4); \
        } \
        { \
            unsigned int u = tile[i][w + 5]; \
            v2f p = { __uint_as_float(u << 16), __uint_as_float(u & 0xffff0000u) }; \
            float g = gw.g[5]; v2f g2 = {g, g}; \
            a01 += g2 * p; \
            a23 += g2 * (p * p); \
            a4  = fmaf(g, p.x * p.y, a4); \
        } \
        r01[(i) % 11] = a01; \
        r23[(i) % 11] = (v2f){ a23.x + a23.y, a4 }; \
        if ((i) >= 10) { \
            const int j = (i) - 10; \
            v2f o01 = {0.f, 0.f}, o23 = {0.f, 0.f}; \
            _Pragma("unroll") \
            for (int k = 0; k < 11; ++k) { \
                float g = gw.g[k]; v2f g2 = {g, g}; \
                o01 += g2 * r01[(j + k) % 11]; \
                o23 += g2 * r23[(j + k) % 11]; \
            } \
            size_t oi = outbase + (size_t)(h0 + j) * WW; \
            ushort4 u4; \
            u4.x = f2bf(o01.x); \
            u4.y = f2bf(o01.y); \
            u4.z = f2bf(o23.x); \
            u4.w = f2bf(o23.y); \
            B4[oi] = u4; \
        } }

        WSTEP(0)  WSTEP(1)  WSTEP(2)  WSTEP(3)  WSTEP(4)  WSTEP(5)
        WSTEP(6)  WSTEP(7)  WSTEP(8)  WSTEP(9)  WSTEP(10) WSTEP(11)
        WSTEP(12) WSTEP(13) WSTEP(14) WSTEP(15) WSTEP(16) WSTEP(17)
        WSTEP(18) WSTEP(19) WSTEP(20) WSTEP(21) WSTEP(22) WSTEP(23)
        WSTEP(24) WSTEP(25)
#undef WSTEP
    }
}

// ---------------- Pass B: D-conv + SSIM + fused finalizer ----------------
// R2 ANCHOR compute verbatim (<83 us per R8's top-5 cutoff -- all prior
// "~123 us" estimates were launch-gap inflation). ONE addition: the k_final
// dispatch is fused via the last-block pattern (release: accum-add,
// threadfence, ctr-add; acquire: coherent read via atomicAdd(accum, 0.0)).
// block 256 (lane -> point p, fully coalesced); grid (100, 4, 4) = 1600 blocks
__global__ __launch_bounds__(256, 4) void k_dssim(
    const ushort4* __restrict__ B4, double* __restrict__ accum,
    unsigned int* __restrict__ ctr, float* __restrict__ out, Gw gw)
{
    const int tid = threadIdx.x;
    const int p   = blockIdx.x * 256 + tid;   // 0..25599
    const int d0  = blockIdx.y * RUN_D;       // 0,40,80,120
    const int n   = blockIdx.z;
    const size_t base = (size_t)n * VOL + p;

    v2f ring01[11], ring23[11];
    float lsum = 0.f;

    // ---- prefetch pipeline: slot q holds slice i with i%PF==q ----
    ushort4 pf[PF];
    {
        const bool front_ok = (d0 != 0);      // slices 0..4 invalid only in seg 0
#pragma unroll
        for (int q = 0; q < PF; ++q) {
            bool ok = (q >= 5) || front_ok;   // q>=5 -> dd = d0+q-5 <= 122, valid
            pf[q] = make_ushort4(0, 0, 0, 0);
            if (ok) {
                size_t idx = base + (size_t)(d0 - 5 + q) * PLANE;
                pf[q] = B4[idx];
            }
        }
    }

#pragma unroll
    for (int i = 0; i < ITERS; ++i) {
        // consume slice i
        ushort4 c4 = pf[i % PF];
        ring01[i%11] = (v2f){ bf2f(c4.x), bf2f(c4.y) };
        ring23[i%11] = (v2f){ bf2f(c4.z), bf2f(c4.w) };

        // refill slot with slice i+PF (dd = d0+i+3); back edge block-uniform
        if (i + PF < ITERS) {
            const int dd = d0 + i + 3;        // compile-time offset per unrolled i
            const bool ok = (dd < 160);       // only last segment ever fails
            pf[i % PF] = make_ushort4(0, 0, 0, 0);
            if (ok) {
                size_t idx = base + (size_t)dd * PLANE;
                pf[i % PF] = B4[idx];
            }
        }

        if (i >= 10) {
            const int j = i - 10;
            v2f o01 = {0.f, 0.f}, o23 = {0.f, 0.f};
#pragma unroll
            for (int k = 0; k < 11; ++k) {
                float g = gw.g[k];
                v2f g2 = {g, g};
                o01 += g2 * ring01[(j + k) % 11];
                o23 += g2 * ring23[(j + k) % 11];
            }
            float mu1 = o01.x, mu2 = o01.y;
            float s   = o23.x, e12 = o23.y;
            float m11  = mu1 * mu2;
            float musq = fmaf(mu1, mu1, mu2 * mu2);
            float num = (2.f * m11 + C1f) * (2.f * (e12 - m11) + C2f);
            float den = (musq + C1f) * ((s - musq) + C2f);
            lsum += num * __builtin_amdgcn_rcpf(den);   // rel err ~1e-5 << 1.9e-2 thr
        }
    }

    // 4-wave block reduce, one atomic, last block finalizes
    __shared__ float wsum[4];
    const int lane = tid & 63, wi = tid >> 6;
#pragma unroll
    for (int off = 32; off > 0; off >>= 1)
        lsum += __shfl_down(lsum, off, 64);
    if (lane == 0) wsum[wi] = lsum;
    __syncthreads();
    if (tid == 0) {
        atomicAdd(accum, (double)(wsum[0] + wsum[1] + wsum[2] + wsum[3]));
        __threadfence();                       // release: accum-add visible first
        unsigned int prev = atomicAdd(ctr, 1u);
        if (prev == NBLK_B - 1) {              // last block of the grid
            __threadfence();                   // acquire
            double tot = atomicAdd(accum, 0.0);  // coherent read (atomic path)
            out[0] = (float)(1.0 - tot / ((double)NBATCH * (double)VOL));
        }
    }
}

extern "C" void kernel_launch(void* const* d_in, const int* in_sizes, int n_in,
                              void* d_out, int out_size, void* d_ws, size_t ws_size,
                              hipStream_t stream)
{
    const float* img1 = (const float*)d_in[0];
    const float* img2 = (const float*)d_in[1];
    float* out = (float*)d_out;

    char* ws = (char*)d_ws;
    ushort4* B4 = (ushort4*)ws;                                   // 4*VOL*8B = 131.07 MB
    double* accum = (double*)(ws + (size_t)NBATCH * VOL * 8);
    unsigned int* ctr = (unsigned int*)(ws + (size_t)NBATCH * VOL * 8 + 8);

    Gw gw;
    {
        double gd[11], s = 0.0;
        for (int i = 0; i < 11; ++i) {
            double t = (double)(i - 5);
            gd[i] = exp(-(t * t) / (2.0 * 1.5 * 1.5));
            s += gd[i];
        }
        for (int i = 0; i < 11; ++i) gw.g[i] = (float)(gd[i] / s);
    }

    // 2 dispatches total (was 4 + memset): ~40 us of launch/gap overhead was
    // measured in R7/R8 wall-clock vs dispatch-duration arithmetic.
    k_wh   <<<dim3(160 / RUN_H, 160, NBATCH), 192, 0, stream>>>(
        img1, img2, B4, gw, accum, ctr);
    k_dssim<<<dim3(PLANE / 256, 160 / RUN_D, NBATCH), 256, 0, stream>>>(
        B4, accum, ctr, out, gw);
}

// Round 10
// 273.398 us; speedup vs baseline: 1.1198x; 1.1198x over previous
//
#include <hip/hip_runtime.h>
#include <hip/hip_bf16.h>
#include <math.h>

#define WW     160
#define NBATCH 4
#define VOL    (160*160*160)      // 4,096,000
#define PLANE  (160*160)

#define C1f 0.0001f
#define C2f 0.0009f

#define RUN_H 16                  // h outputs per k_wh block
#define NROWS (RUN_H + 10)        // 26 rows staged
#define LDW   176                 // padded cols: [0..4]=0, [5..164]=data, [165..175]=0
#define RUN_D 40                  // d outputs per k_dssim block (4 segments)
#define ITERS (RUN_D + 10)        // 50
#define PF    8                   // prefetch slots (R2 anchor)

typedef float v2f __attribute__((ext_vector_type(2)));

struct Gw { float g[11]; };

__device__ __forceinline__ float bf2f(unsigned short u) {
    return __uint_as_float(((unsigned int)u) << 16);
}
__device__ __forceinline__ unsigned short f2bf(float f) {
    __hip_bfloat16 h = __float2bfloat16(f);   // RNE
    return *reinterpret_cast<unsigned short*>(&h);
}

// Packed-f32 VALU (VOP3P). hipcc scalarizes ext_vector float2 math (R9
// accounting: ~4700 VALU/wave measured ~= scalarized estimate, not packed);
// these force v_pk_*_f32, halving the W-conv/H-dot FMA stream.
__device__ __forceinline__ v2f pk_add(v2f a, v2f b) {
    v2f d; asm("v_pk_add_f32 %0, %1, %2" : "=v"(d) : "v"(a), "v"(b)); return d;
}
__device__ __forceinline__ v2f pk_mul(v2f a, v2f b) {
    v2f d; asm("v_pk_mul_f32 %0, %1, %2" : "=v"(d) : "v"(a), "v"(b)); return d;
}
__device__ __forceinline__ v2f pk_fma(v2f a, v2f b, v2f c) {
    v2f d; asm("v_pk_fma_f32 %0, %1, %2, %3" : "=v"(d) : "v"(a), "v"(b), "v"(c)); return d;
}

// ---------------- Pass A: W+H conv fused; bf16x2-packed LDS tile ----------------
// R2 structure (148.3 us anchor); CHANGE: packed-f32 inline asm for the conv
// arithmetic + hoisted {g,g} constant pairs. Staging, tile, rings unchanged.
// Block (0,0,0) zeroes accum (fence-free memset replacement; stream order
// guarantees k_dssim sees it. R9's fused-finalizer threadfence is REVERTED --
// its per-block device fence invalidated L2 under co-resident readers).
// block 192 (3 waves; threads 0..159 compute, all 192 load)
// grid (10, d=160, batch=4) = 6400 blocks; LDS 18.3 KB -> 8 blocks/CU.
__global__ __launch_bounds__(192, 4) void k_wh(
    const float* __restrict__ x, const float* __restrict__ y,
    ushort4* __restrict__ B4, Gw gw, double* __restrict__ accum)
{
    __shared__ unsigned int tile[NROWS][LDW];   // 26*176*4 = 18.3 KB
    const int t  = threadIdx.x;
    const int h0 = blockIdx.x * RUN_H;
    const int d  = blockIdx.y;
    const int n  = blockIdx.z;

    if (t == 0 && blockIdx.x == 0 && d == 0 && n == 0)
        accum[0] = 0.0;         // replaces hipMemsetAsync dispatch (no fence)

    const float* xb = x + (size_t)n * VOL + (size_t)d * PLANE;
    const float* yb = y + (size_t)n * VOL + (size_t)d * PLANE;

    // ---- fill tile: independent coalesced loads, pack bf16(y)<<16 | bf16(x) ----
#pragma unroll 4
    for (int s = t; s < NROWS * LDW; s += 192) {
        int r = s / LDW, c = s - r * LDW;
        int h = h0 - 5 + r;
        int w = c - 5;
        float vx = 0.f, vy = 0.f;
        if (h >= 0 && h < 160 && w >= 0 && w < 160) {
            size_t idx = (size_t)h * WW + w;
            vx = xb[idx];
            vy = yb[idx];
        }
        tile[r][c] = ((unsigned int)f2bf(vy) << 16) | (unsigned int)f2bf(vx);
    }
    __syncthreads();

    // ---- compute: LDS u32 taps (2-bitop unpack) + v_pk_*_f32 VALU ----
    if (t < 160) {
        const int w = t;
        const size_t outbase = (size_t)n * VOL + (size_t)d * PLANE + w;
        v2f r01[11];          // ring: {conv(x), conv(y)}
        v2f r23[11];          // ring: {conv(x^2)+conv(y^2), conv(xy)} packed

        // 6 unique gaussian weights as {g,g} VGPR pairs, built once.
        v2f g2c[6];
#pragma unroll
        for (int k = 0; k < 6; ++k) g2c[k] = (v2f){gw.g[k], gw.g[k]};

        // Macro-unrolled rows: every ring index is a literal.
#define WSTEP(i) { \
        v2f a01 = {0.f, 0.f}, a23 = {0.f, 0.f}; float a4 = 0.f; \
        _Pragma("unroll") \
        for (int k = 0; k < 5; ++k) { \
            unsigned int u1 = tile[i][w + k]; \
            unsigned int u2 = tile[i][w + 10 - k]; \
            v2f p1 = { __uint_as_float(u1 << 16), __uint_as_float(u1 & 0xffff0000u) }; \
            v2f p2 = { __uint_as_float(u2 << 16), __uint_as_float(u2 & 0xffff0000u) }; \
            a01 = pk_fma(g2c[k], pk_add(p1, p2), a01); \
            v2f sq = pk_fma(p2, p2, pk_mul(p1, p1)); \
            a23 = pk_fma(g2c[k], sq, a23); \
            float pr = p1.x * p1.y; \
            pr = fmaf(p2.x, p2.y, pr); \
            a4 = fmaf(gw.g[k], pr, a4); \
        } \
        { \
            unsigned int u = tile[i][w + 5]; \
            v2f p = { __uint_as_float(u << 16), __uint_as_float(u & 0xffff0000u) }; \
            a01 = pk_fma(g2c[5], p, a01); \
            a23 = pk_fma(g2c[5], pk_mul(p, p), a23); \
            a4  = fmaf(gw.g[5], p.x * p.y, a4); \
        } \
        r01[(i) % 11] = a01; \
        r23[(i) % 11] = (v2f){ a23.x + a23.y, a4 }; \
        if ((i) >= 10) { \
            const int j = (i) - 10; \
            v2f o01 = {0.f, 0.f}, o23 = {0.f, 0.f}; \
            _Pragma("unroll") \
            for (int k = 0; k < 11; ++k) { \
                v2f gk = g2c[(k < 6) ? k : 10 - k]; \
                o01 = pk_fma(gk, r01[(j + k) % 11], o01); \
                o23 = pk_fma(gk, r23[(j + k) % 11], o23); \
            } \
            size_t oi = outbase + (size_t)(h0 + j) * WW; \
            ushort4 u4; \
            u4.x = f2bf(o01.x); \
            u4.y = f2bf(o01.y); \
            u4.z = f2bf(o23.x); \
            u4.w = f2bf(o23.y); \
            B4[oi] = u4; \
        } }

        WSTEP(0)  WSTEP(1)  WSTEP(2)  WSTEP(3)  WSTEP(4)  WSTEP(5)
        WSTEP(6)  WSTEP(7)  WSTEP(8)  WSTEP(9)  WSTEP(10) WSTEP(11)
        WSTEP(12) WSTEP(13) WSTEP(14) WSTEP(15) WSTEP(16) WSTEP(17)
        WSTEP(18) WSTEP(19) WSTEP(20) WSTEP(21) WSTEP(22) WSTEP(23)
        WSTEP(24) WSTEP(25)
#undef WSTEP
    }
}

// ---------------- Pass B: D-conv + SSIM; 4ch, PF=8 pipeline, rcp ----------------
// R2 ANCHOR VERBATIM (<83 us per R8 evidence). R9's fused finalizer reverted.
// block 256 (lane -> point p, fully coalesced); grid (100, 4, 4) = 1600 blocks
__global__ __launch_bounds__(256, 4) void k_dssim(
    const ushort4* __restrict__ B4, double* __restrict__ accum, Gw gw)
{
    const int tid = threadIdx.x;
    const int p   = blockIdx.x * 256 + tid;   // 0..25599
    const int d0  = blockIdx.y * RUN_D;       // 0,40,80,120
    const int n   = blockIdx.z;
    const size_t base = (size_t)n * VOL + p;

    v2f ring01[11], ring23[11];
    float lsum = 0.f;

    // ---- prefetch pipeline: slot q holds slice i with i%PF==q ----
    ushort4 pf[PF];
    {
        const bool front_ok = (d0 != 0);      // slices 0..4 invalid only in seg 0
#pragma unroll
        for (int q = 0; q < PF; ++q) {
            bool ok = (q >= 5) || front_ok;   // q>=5 -> dd = d0+q-5 <= 122, valid
            pf[q] = make_ushort4(0, 0, 0, 0);
            if (ok) {
                size_t idx = base + (size_t)(d0 - 5 + q) * PLANE;
                pf[q] = B4[idx];
            }
        }
    }

#pragma unroll
    for (int i = 0; i < ITERS; ++i) {
        // consume slice i
        ushort4 c4 = pf[i % PF];
        ring01[i%11] = (v2f){ bf2f(c4.x), bf2f(c4.y) };
        ring23[i%11] = (v2f){ bf2f(c4.z), bf2f(c4.w) };

        // refill slot with slice i+PF (dd = d0+i+3); back edge block-uniform
        if (i + PF < ITERS) {
            const int dd = d0 + i + 3;        // compile-time offset per unrolled i
            const bool ok = (dd < 160);       // only last segment ever fails
            pf[i % PF] = make_ushort4(0, 0, 0, 0);
            if (ok) {
                size_t idx = base + (size_t)dd * PLANE;
                pf[i % PF] = B4[idx];
            }
        }

        if (i >= 10) {
            const int j = i - 10;
            v2f o01 = {0.f, 0.f}, o23 = {0.f, 0.f};
#pragma unroll
            for (int k = 0; k < 11; ++k) {
                float g = gw.g[k];
                v2f g2 = {g, g};
                o01 += g2 * ring01[(j + k) % 11];
                o23 += g2 * ring23[(j + k) % 11];
            }
            float mu1 = o01.x, mu2 = o01.y;
            float s   = o23.x, e12 = o23.y;
            float m11  = mu1 * mu2;
            float musq = fmaf(mu1, mu1, mu2 * mu2);
            float num = (2.f * m11 + C1f) * (2.f * (e12 - m11) + C2f);
            float den = (musq + C1f) * ((s - musq) + C2f);
            lsum += num * __builtin_amdgcn_rcpf(den);   // rel err ~1e-5 << 1.9e-2 thr
        }
    }

    // 4-wave block reduce, one atomic
    __shared__ float wsum[4];
    const int lane = tid & 63, wi = tid >> 6;
#pragma unroll
    for (int off = 32; off > 0; off >>= 1)
        lsum += __shfl_down(lsum, off, 64);
    if (lane == 0) wsum[wi] = lsum;
    __syncthreads();
    if (tid == 0)
        atomicAdd(accum, (double)(wsum[0] + wsum[1] + wsum[2] + wsum[3]));
}

__global__ void k_final(const double* __restrict__ accum, float* __restrict__ out)
{
    out[0] = (float)(1.0 - accum[0] / ((double)NBATCH * (double)VOL));
}

extern "C" void kernel_launch(void* const* d_in, const int* in_sizes, int n_in,
                              void* d_out, int out_size, void* d_ws, size_t ws_size,
                              hipStream_t stream)
{
    const float* img1 = (const float*)d_in[0];
    const float* img2 = (const float*)d_in[1];
    float* out = (float*)d_out;

    char* ws = (char*)d_ws;
    ushort4* B4 = (ushort4*)ws;                                   // 4*VOL*8B = 131.07 MB
    double* accum = (double*)(ws + (size_t)NBATCH * VOL * 8);

    Gw gw;
    {
        double gd[11], s = 0.0;
        for (int i = 0; i < 11; ++i) {
            double t = (double)(i - 5);
            gd[i] = exp(-(t * t) / (2.0 * 1.5 * 1.5));
            s += gd[i];
        }
        for (int i = 0; i < 11; ++i) gw.g[i] = (float)(gd[i] / s);
    }

    k_wh   <<<dim3(160 / RUN_H, 160, NBATCH), 192, 0, stream>>>(
        img1, img2, B4, gw, accum);
    k_dssim<<<dim3(PLANE / 256, 160 / RUN_D, NBATCH), 256, 0, stream>>>(B4, accum, gw);
    k_final<<<1, 1, 0, stream>>>(accum, out);
}